// Round 4
// baseline (5208.862 us; speedup 1.0000x reference)
//
#include <hip/hip_runtime.h>
#include <math.h>

#define NEG_SLOPE 0.2f
#define NXCD 8

// ---------------------------------------------------------------------------
// Register-tiled GEMM + fused attention logits.
//   H[n,64] = X[n,K] @ W[K,64];  As[n] = H.att_s;  Ad[n] = H.att_d
// ---------------------------------------------------------------------------
template <int K>
__global__ __launch_bounds__(256) void gemm_tile(
    const float* __restrict__ X, const float* __restrict__ W,
    const float* __restrict__ att_s, const float* __restrict__ att_d,
    float* __restrict__ H, float* __restrict__ As, float* __restrict__ Ad,
    int n)
{
    constexpr int XP = K + 4;
    constexpr int BK = 64;
    __shared__ float Xs[64 * XP];
    __shared__ float Ws[BK * 64];

    const int tid = threadIdx.x;
    const int node0 = blockIdx.x * 64;

    for (int i4 = tid; i4 < 64 * (K / 4); i4 += 256) {
        int r = i4 / (K / 4);
        int c = (i4 % (K / 4)) * 4;
        int nd = node0 + r;
        float4 v = make_float4(0.f, 0.f, 0.f, 0.f);
        if (nd < n) v = *(const float4*)&X[(size_t)nd * K + c];
        *(float4*)&Xs[r * XP + c] = v;
    }

    const int tx = tid & 15;
    const int ty = tid >> 4;

    float acc[4][4];
#pragma unroll
    for (int r = 0; r < 4; ++r)
#pragma unroll
        for (int f = 0; f < 4; ++f) acc[r][f] = 0.0f;

    for (int kc = 0; kc < K; kc += BK) {
        __syncthreads();
        for (int i = tid; i < BK * 64; i += 256) Ws[i] = W[kc * 64 + i];
        __syncthreads();

        for (int k = 0; k < BK; k += 4) {
            float4 a0 = *(const float4*)&Xs[(ty * 4 + 0) * XP + kc + k];
            float4 a1 = *(const float4*)&Xs[(ty * 4 + 1) * XP + kc + k];
            float4 a2 = *(const float4*)&Xs[(ty * 4 + 2) * XP + kc + k];
            float4 a3 = *(const float4*)&Xs[(ty * 4 + 3) * XP + kc + k];
            float4 b0 = *(const float4*)&Ws[(k + 0) * 64 + tx * 4];
            float4 b1 = *(const float4*)&Ws[(k + 1) * 64 + tx * 4];
            float4 b2 = *(const float4*)&Ws[(k + 2) * 64 + tx * 4];
            float4 b3 = *(const float4*)&Ws[(k + 3) * 64 + tx * 4];
#define GEMM_ROW(rr, av)                                                     \
            acc[rr][0] = fmaf(av.x, b0.x, acc[rr][0]);                       \
            acc[rr][1] = fmaf(av.x, b0.y, acc[rr][1]);                       \
            acc[rr][2] = fmaf(av.x, b0.z, acc[rr][2]);                       \
            acc[rr][3] = fmaf(av.x, b0.w, acc[rr][3]);                       \
            acc[rr][0] = fmaf(av.y, b1.x, acc[rr][0]);                       \
            acc[rr][1] = fmaf(av.y, b1.y, acc[rr][1]);                       \
            acc[rr][2] = fmaf(av.y, b1.z, acc[rr][2]);                       \
            acc[rr][3] = fmaf(av.y, b1.w, acc[rr][3]);                       \
            acc[rr][0] = fmaf(av.z, b2.x, acc[rr][0]);                       \
            acc[rr][1] = fmaf(av.z, b2.y, acc[rr][1]);                       \
            acc[rr][2] = fmaf(av.z, b2.z, acc[rr][2]);                       \
            acc[rr][3] = fmaf(av.z, b2.w, acc[rr][3]);                       \
            acc[rr][0] = fmaf(av.w, b3.x, acc[rr][0]);                       \
            acc[rr][1] = fmaf(av.w, b3.y, acc[rr][1]);                       \
            acc[rr][2] = fmaf(av.w, b3.z, acc[rr][2]);                       \
            acc[rr][3] = fmaf(av.w, b3.w, acc[rr][3]);
            GEMM_ROW(0, a0)
            GEMM_ROW(1, a1)
            GEMM_ROW(2, a2)
            GEMM_ROW(3, a3)
#undef GEMM_ROW
        }
    }

    float4 ats = *(const float4*)&att_s[tx * 4];
    float4 atd = *(const float4*)&att_d[tx * 4];
#pragma unroll
    for (int rr = 0; rr < 4; ++rr) {
        int nd = node0 + ty * 4 + rr;
        float vs = acc[rr][0] * ats.x + acc[rr][1] * ats.y +
                   acc[rr][2] * ats.z + acc[rr][3] * ats.w;
        float vd = acc[rr][0] * atd.x + acc[rr][1] * atd.y +
                   acc[rr][2] * atd.z + acc[rr][3] * atd.w;
#pragma unroll
        for (int off = 8; off; off >>= 1) {
            vs += __shfl_xor(vs, off);
            vd += __shfl_xor(vd, off);
        }
        if (nd < n) {
            float4 hv = make_float4(acc[rr][0], acc[rr][1], acc[rr][2], acc[rr][3]);
            *(float4*)&H[(size_t)nd * 64 + tx * 4] = hv;
            if (tx == 0) { As[nd] = vs; Ad[nd] = vd; }
        }
    }
}

// ---------------------------------------------------------------------------
// Phase 1: bin edges into NXCD dst-range buckets. Wave-aggregated append:
// per bucket, ballot -> leader atomicAdd -> contiguous burst write (~8
// records = 64B per bucket per wave) at a monotonically advancing frontier.
// ---------------------------------------------------------------------------
__global__ __launch_bounds__(256) void bin_kernel(
    const int* __restrict__ src, const int* __restrict__ dst, int e,
    int* __restrict__ bin_cnt, int2* __restrict__ bins, int cap, int lo_div)
{
    const int lane = threadIdx.x & 63;
    const unsigned long long ltmask =
        (lane == 0) ? 0ull : (~0ull >> (64 - lane));
    const int stride = gridDim.x * blockDim.x;

    for (int i = blockIdx.x * blockDim.x + threadIdx.x; i < e; i += stride) {
        int s = __builtin_nontemporal_load(&src[i]);
        int d = __builtin_nontemporal_load(&dst[i]);
        int g = d / lo_div;
        int2 r; r.x = s; r.y = d;
#pragma unroll
        for (int b = 0; b < NXCD; ++b) {
            unsigned long long mask = __ballot(g == b);
            if (mask) {
                int leader = __ffsll((long long)mask) - 1;
                int base = 0;
                if (lane == leader) base = atomicAdd(&bin_cnt[b], __popcll(mask));
                base = __shfl(base, leader);
                if (g == b) {
                    int off = __popcll(mask & ltmask);
                    bins[(size_t)b * cap + base + off] = r;
                }
            }
        }
    }
}

// ---------------------------------------------------------------------------
// Phase 2a: XCD-local histogram over the group's bucket (deg range ~50KB
// stays in the XCD's L2).
// ---------------------------------------------------------------------------
__global__ __launch_bounds__(256) void hist2_kernel(
    const int* __restrict__ bin_cnt, const int2* __restrict__ bins, int cap,
    int* __restrict__ deg)
{
    const int g = blockIdx.x & (NXCD - 1);
    const int gi = blockIdx.x >> 3;
    const int nb = gridDim.x >> 3;
    const int cnt = bin_cnt[g];
    const int2* bk = bins + (size_t)g * cap;
    for (int i = gi * 256 + threadIdx.x; i < cnt; i += nb * 256)
        atomicAdd(&deg[bk[i].y], 1);
}

#define SCAN_B 256
#define SCAN_E 1024  // 4 elems per thread

__global__ __launch_bounds__(SCAN_B) void scan1_kernel(
    const int* __restrict__ deg, int n, int* __restrict__ out /* = rp+1 */,
    int* __restrict__ partials)
{
    __shared__ int sh[SCAN_B];
    const int b = blockIdx.x, t = threadIdx.x;
    const int base = b * SCAN_E + t * 4;
    int v[4];
#pragma unroll
    for (int i = 0; i < 4; ++i) {
        int idx = base + i;
        v[i] = (idx < n) ? deg[idx] : 0;
    }
    v[1] += v[0]; v[2] += v[1]; v[3] += v[2];
    sh[t] = v[3];
    __syncthreads();
    for (int off = 1; off < SCAN_B; off <<= 1) {
        int x = (t >= off) ? sh[t - off] : 0;
        __syncthreads();
        sh[t] += x;
        __syncthreads();
    }
    int excl = (t > 0) ? sh[t - 1] : 0;
#pragma unroll
    for (int i = 0; i < 4; ++i) {
        int idx = base + i;
        if (idx < n) out[idx] = v[i] + excl;  // inclusive
    }
    if (t == SCAN_B - 1) partials[b] = sh[t];
}

__global__ __launch_bounds__(256) void scan2_kernel(int* __restrict__ partials, int nb)
{
    __shared__ int sh[256];
    const int t = threadIdx.x;
    int v = (t < nb) ? partials[t] : 0;
    sh[t] = v;
    __syncthreads();
    for (int off = 1; off < 256; off <<= 1) {
        int x = (t >= off) ? sh[t - off] : 0;
        __syncthreads();
        sh[t] += x;
        __syncthreads();
    }
    if (t < nb) partials[t] = (t > 0) ? sh[t - 1] : 0;  // exclusive
}

__global__ void scan3_kernel(int* __restrict__ rp, int* __restrict__ cursor,
                             int n, const int* __restrict__ partials)
{
    int i = blockIdx.x * blockDim.x + threadIdx.x;
    if (i < n) {
        int v = rp[1 + i] + partials[i >> 10];
        rp[1 + i] = v;
        if (i + 1 < n) cursor[i + 1] = v;
    }
    if (i == 0) { rp[0] = 0; cursor[0] = 0; }
}

// ---------------------------------------------------------------------------
// Phase 2b: XCD-local scatter. Group g streams its 1.6MB bucket and writes
// {src, leakyrelu(As[src]+Ad[dst])} into its 1.6MB rec region. Whole working
// set (~3.7MB) fits the XCD's 4MB L2 -> rec lines accumulate fully.
// ---------------------------------------------------------------------------
__global__ __launch_bounds__(256) void scatter2_kernel(
    const int* __restrict__ bin_cnt, const int2* __restrict__ bins, int cap,
    int* __restrict__ cursor, int2* __restrict__ rec,
    const float* __restrict__ As, const float* __restrict__ Ad)
{
    const int g = blockIdx.x & (NXCD - 1);
    const int gi = blockIdx.x >> 3;
    const int nb = gridDim.x >> 3;
    const int cnt = bin_cnt[g];
    const int2* bk = bins + (size_t)g * cap;

    for (int i = gi * 256 + threadIdx.x; i < cnt; i += nb * 256) {
        int2 r = bk[i];
        float ev = As[r.x] + Ad[r.y];
        ev = (ev >= 0.0f) ? ev : NEG_SLOPE * ev;
        int pos = atomicAdd(&cursor[r.y], 1);
        int2 o; o.x = r.x; o.y = __float_as_int(ev);
        rec[pos] = o;
    }
}

// ---------------------------------------------------------------------------
// Aggregation: one wave per destination node, XCD-swizzled.
// ---------------------------------------------------------------------------
__global__ __launch_bounds__(256) void aggr_kernel(
    const int* __restrict__ rp, const int2* __restrict__ rec,
    const float* __restrict__ Hin, const float* __restrict__ bias,
    float* __restrict__ Out, int n, int lo_div, int relu_flag)
{
    const int lane = threadIdx.x & 63;
    const int wv = threadIdx.x >> 6;
    const float b = bias[lane];

    const int g = blockIdx.x & (NXCD - 1);
    const int gi = blockIdx.x >> 3;
    const int ngb = gridDim.x >> 3;
    const int lo = g * lo_div;
    const int hi = min(lo + lo_div, n);

    for (int d = lo + gi * 4 + wv; d < hi; d += ngb * 4) {
        const int beg = rp[d], end = rp[d + 1];

        float m = -1e30f, s = 0.0f;
        for (int i = beg + lane; i < end; i += 64) {
            float e = __int_as_float(rec[i].y);
            float mn = fmaxf(m, e);
            s = s * __expf(m - mn) + __expf(e - mn);
            m = mn;
        }
#pragma unroll
        for (int off = 32; off; off >>= 1) {
            float mo = __shfl_xor(m, off);
            float so = __shfl_xor(s, off);
            float mn = fmaxf(m, mo);
            s = s * __expf(m - mn) + so * __expf(mo - mn);
            m = mn;
        }
        const float inv = 1.0f / (s + 1e-16f);

        float acc0 = 0.f, acc1 = 0.f, acc2 = 0.f, acc3 = 0.f;
        int i = beg;
        for (; i + 4 <= end; i += 4) {
            int2 r0 = rec[i + 0];
            int2 r1 = rec[i + 1];
            int2 r2 = rec[i + 2];
            int2 r3 = rec[i + 3];
            float w0 = __expf(__int_as_float(r0.y) - m) * inv;
            float w1 = __expf(__int_as_float(r1.y) - m) * inv;
            float w2 = __expf(__int_as_float(r2.y) - m) * inv;
            float w3 = __expf(__int_as_float(r3.y) - m) * inv;
            acc0 = fmaf(w0, Hin[(size_t)r0.x * 64 + lane], acc0);
            acc1 = fmaf(w1, Hin[(size_t)r1.x * 64 + lane], acc1);
            acc2 = fmaf(w2, Hin[(size_t)r2.x * 64 + lane], acc2);
            acc3 = fmaf(w3, Hin[(size_t)r3.x * 64 + lane], acc3);
        }
        for (; i < end; ++i) {
            int2 r = rec[i];
            float w = __expf(__int_as_float(r.y) - m) * inv;
            acc0 = fmaf(w, Hin[(size_t)r.x * 64 + lane], acc0);
        }

        float r = (acc0 + acc1) + (acc2 + acc3) + b;
        if (relu_flag) r = fmaxf(r, 0.0f);
        Out[(size_t)d * 64 + lane] = r;
    }
}

// ---------------------------------------------------------------------------
// Final linear [64 -> 32] + log_softmax.
// ---------------------------------------------------------------------------
__global__ __launch_bounds__(256) void lin_lsm_kernel(
    const float* __restrict__ Z, const float* __restrict__ Wl,
    const float* __restrict__ bl, float* __restrict__ out, int n)
{
    __shared__ float Ws[64 * 32];
    __shared__ float bs[32];
    for (int i = threadIdx.x; i < 64 * 32; i += 256) Ws[i] = Wl[i];
    if (threadIdx.x < 32) bs[threadIdx.x] = bl[threadIdx.x];
    __syncthreads();

    const int lane = threadIdx.x & 63;
    const int wv = threadIdx.x >> 6;
    const int half = lane >> 5;
    const int o = lane & 31;

    for (int base = (blockIdx.x * 4 + wv) * 2; base < n; base += gridDim.x * 8) {
        const int nd = base + half;
        float acc = 0.0f;
        if (nd < n) {
            const float* z = Z + (size_t)nd * 64;
#pragma unroll
            for (int k = 0; k < 64; ++k)
                acc = fmaf(z[k], Ws[k * 32 + o], acc);
            acc += bs[o];
        }
        float m = acc;
#pragma unroll
        for (int off = 16; off; off >>= 1) m = fmaxf(m, __shfl_xor(m, off, 32));
        float ex = __expf(acc - m);
        float s = ex;
#pragma unroll
        for (int off = 16; off; off >>= 1) s += __shfl_xor(s, off, 32);
        if (nd < n) out[(size_t)nd * 32 + o] = acc - m - logf(s);
    }
}

// ---------------------------------------------------------------------------
extern "C" void kernel_launch(void* const* d_in, const int* in_sizes, int n_in,
                              void* d_out, int out_size, void* d_ws, size_t ws_size,
                              hipStream_t stream)
{
    const float* x        = (const float*)d_in[0];
    const int*   ei1      = (const int*)d_in[1];
    const int*   ei2      = (const int*)d_in[2];
    const float* W1       = (const float*)d_in[3];
    const float* att_src1 = (const float*)d_in[4];
    const float* att_dst1 = (const float*)d_in[5];
    const float* b1       = (const float*)d_in[6];
    const float* W2       = (const float*)d_in[7];
    const float* att_src2 = (const float*)d_in[8];
    const float* att_dst2 = (const float*)d_in[9];
    const float* b2       = (const float*)d_in[10];
    const float* Wlin     = (const float*)d_in[11];
    const float* blin     = (const float*)d_in[12];
    float* out = (float*)d_out;

    const int n = in_sizes[0] / 128;   // 100000
    const int e = in_sizes[1] / 2;     // 1600000

    size_t off = 0;
    auto alloc = [&](size_t bytes) {
        void* p = (char*)d_ws + off;
        off += (bytes + 255) & ~(size_t)255;
        return p;
    };
    float* bufH  = (float*)alloc((size_t)n * 64 * 4);
    float* bufZ  = (float*)alloc((size_t)n * 64 * 4);
    float* As    = (float*)alloc((size_t)n * 4);
    float* Ad    = (float*)alloc((size_t)n * 4);
    int* deg     = (int*)alloc((size_t)n * 4);
    int* rp      = (int*)alloc((size_t)(n + 1) * 4);
    int* cursor  = (int*)alloc((size_t)n * 4);
    int* partials= (int*)alloc(256 * 4);
    int* bin_cnt = (int*)alloc(NXCD * 4);
    int2* rec    = (int2*)alloc((size_t)e * 8);
    // buckets alias bufZ (dead during binning in both layers)
    const int cap = e / NXCD + 65536;          // 8*cap*8B = 17MB <= 25.6MB
    int2* bins   = (int2*)bufZ;

    const int nb_scan = (n + SCAN_E - 1) / SCAN_E;
    const int gN = (n + 255) / 256;
    const int gTile = (n + 63) / 64;
    const int lo_div = (n + NXCD - 1) / NXCD;
    const int gAggr = NXCD * ((lo_div + 3) / 4);
    const int gBin = 1024;
    const int gLoc = 2048;  // XCD-swizzled kernels (multiple of 8)

    // ---------------- Layer 1 ----------------
    hipMemsetAsync(deg, 0, (size_t)n * 4, stream);
    hipMemsetAsync(bin_cnt, 0, NXCD * 4, stream);
    bin_kernel<<<gBin, 256, 0, stream>>>(ei1, ei1 + e, e, bin_cnt, bins, cap, lo_div);
    gemm_tile<128><<<gTile, 256, 0, stream>>>(x, W1, att_src1, att_dst1, bufH, As, Ad, n);
    hist2_kernel<<<gLoc, 256, 0, stream>>>(bin_cnt, bins, cap, deg);
    scan1_kernel<<<nb_scan, SCAN_B, 0, stream>>>(deg, n, rp + 1, partials);
    scan2_kernel<<<1, 256, 0, stream>>>(partials, nb_scan);
    scan3_kernel<<<gN, 256, 0, stream>>>(rp, cursor, n, partials);
    scatter2_kernel<<<gLoc, 256, 0, stream>>>(bin_cnt, bins, cap, cursor, rec, As, Ad);
    aggr_kernel<<<gAggr, 256, 0, stream>>>(rp, rec, bufH, b1, bufZ, n, lo_div, 1);

    // ---------------- Layer 2 ----------------
    hipMemsetAsync(deg, 0, (size_t)n * 4, stream);
    hipMemsetAsync(bin_cnt, 0, NXCD * 4, stream);
    gemm_tile<64><<<gTile, 256, 0, stream>>>(bufZ, W2, att_src2, att_dst2, bufH, As, Ad, n);
    bin_kernel<<<gBin, 256, 0, stream>>>(ei2, ei2 + e, e, bin_cnt, bins, cap, lo_div);
    hist2_kernel<<<gLoc, 256, 0, stream>>>(bin_cnt, bins, cap, deg);
    scan1_kernel<<<nb_scan, SCAN_B, 0, stream>>>(deg, n, rp + 1, partials);
    scan2_kernel<<<1, 256, 0, stream>>>(partials, nb_scan);
    scan3_kernel<<<gN, 256, 0, stream>>>(rp, cursor, n, partials);
    scatter2_kernel<<<gLoc, 256, 0, stream>>>(bin_cnt, bins, cap, cursor, rec, As, Ad);
    aggr_kernel<<<gAggr, 256, 0, stream>>>(rp, rec, bufH, b2, bufZ, n, lo_div, 0);

    // ---------------- Final linear + log_softmax ----------------
    const int gLSM = (n + 7) / 8;
    lin_lsm_kernel<<<gLSM, 256, 0, stream>>>(bufZ, Wlin, blin, out, n);
}

// Round 5
// 719.423 us; speedup vs baseline: 7.2403x; 7.2403x over previous
//
#include <hip/hip_runtime.h>
#include <math.h>

#define NEG_SLOPE 0.2f
#define NXCD 8
#define GRIDB 1024   // blocks for the binning pass (fixed; cnts layout depends on it)

// ---------------------------------------------------------------------------
// Register-tiled GEMM + fused attention logits.
//   H[n,64] = X[n,K] @ W[K,64];  As[n] = H.att_s;  Ad[n] = H.att_d
// ---------------------------------------------------------------------------
template <int K>
__global__ __launch_bounds__(256) void gemm_tile(
    const float* __restrict__ X, const float* __restrict__ W,
    const float* __restrict__ att_s, const float* __restrict__ att_d,
    float* __restrict__ H, float* __restrict__ As, float* __restrict__ Ad,
    int n)
{
    constexpr int XP = K + 4;
    constexpr int BK = 64;
    __shared__ float Xs[64 * XP];
    __shared__ float Ws[BK * 64];

    const int tid = threadIdx.x;
    const int node0 = blockIdx.x * 64;

    for (int i4 = tid; i4 < 64 * (K / 4); i4 += 256) {
        int r = i4 / (K / 4);
        int c = (i4 % (K / 4)) * 4;
        int nd = node0 + r;
        float4 v = make_float4(0.f, 0.f, 0.f, 0.f);
        if (nd < n) v = *(const float4*)&X[(size_t)nd * K + c];
        *(float4*)&Xs[r * XP + c] = v;
    }

    const int tx = tid & 15;
    const int ty = tid >> 4;

    float acc[4][4];
#pragma unroll
    for (int r = 0; r < 4; ++r)
#pragma unroll
        for (int f = 0; f < 4; ++f) acc[r][f] = 0.0f;

    for (int kc = 0; kc < K; kc += BK) {
        __syncthreads();
        for (int i = tid; i < BK * 64; i += 256) Ws[i] = W[kc * 64 + i];
        __syncthreads();

        for (int k = 0; k < BK; k += 4) {
            float4 a0 = *(const float4*)&Xs[(ty * 4 + 0) * XP + kc + k];
            float4 a1 = *(const float4*)&Xs[(ty * 4 + 1) * XP + kc + k];
            float4 a2 = *(const float4*)&Xs[(ty * 4 + 2) * XP + kc + k];
            float4 a3 = *(const float4*)&Xs[(ty * 4 + 3) * XP + kc + k];
            float4 b0 = *(const float4*)&Ws[(k + 0) * 64 + tx * 4];
            float4 b1 = *(const float4*)&Ws[(k + 1) * 64 + tx * 4];
            float4 b2 = *(const float4*)&Ws[(k + 2) * 64 + tx * 4];
            float4 b3 = *(const float4*)&Ws[(k + 3) * 64 + tx * 4];
#define GEMM_ROW(rr, av)                                                     \
            acc[rr][0] = fmaf(av.x, b0.x, acc[rr][0]);                       \
            acc[rr][1] = fmaf(av.x, b0.y, acc[rr][1]);                       \
            acc[rr][2] = fmaf(av.x, b0.z, acc[rr][2]);                       \
            acc[rr][3] = fmaf(av.x, b0.w, acc[rr][3]);                       \
            acc[rr][0] = fmaf(av.y, b1.x, acc[rr][0]);                       \
            acc[rr][1] = fmaf(av.y, b1.y, acc[rr][1]);                       \
            acc[rr][2] = fmaf(av.y, b1.z, acc[rr][2]);                       \
            acc[rr][3] = fmaf(av.y, b1.w, acc[rr][3]);                       \
            acc[rr][0] = fmaf(av.z, b2.x, acc[rr][0]);                       \
            acc[rr][1] = fmaf(av.z, b2.y, acc[rr][1]);                       \
            acc[rr][2] = fmaf(av.z, b2.z, acc[rr][2]);                       \
            acc[rr][3] = fmaf(av.z, b2.w, acc[rr][3]);                       \
            acc[rr][0] = fmaf(av.w, b3.x, acc[rr][0]);                       \
            acc[rr][1] = fmaf(av.w, b3.y, acc[rr][1]);                       \
            acc[rr][2] = fmaf(av.w, b3.z, acc[rr][2]);                       \
            acc[rr][3] = fmaf(av.w, b3.w, acc[rr][3]);
            GEMM_ROW(0, a0)
            GEMM_ROW(1, a1)
            GEMM_ROW(2, a2)
            GEMM_ROW(3, a3)
#undef GEMM_ROW
        }
    }

    float4 ats = *(const float4*)&att_s[tx * 4];
    float4 atd = *(const float4*)&att_d[tx * 4];
#pragma unroll
    for (int rr = 0; rr < 4; ++rr) {
        int nd = node0 + ty * 4 + rr;
        float vs = acc[rr][0] * ats.x + acc[rr][1] * ats.y +
                   acc[rr][2] * ats.z + acc[rr][3] * ats.w;
        float vd = acc[rr][0] * atd.x + acc[rr][1] * atd.y +
                   acc[rr][2] * atd.z + acc[rr][3] * atd.w;
#pragma unroll
        for (int off = 8; off; off >>= 1) {
            vs += __shfl_xor(vs, off);
            vd += __shfl_xor(vd, off);
        }
        if (nd < n) {
            float4 hv = make_float4(acc[rr][0], acc[rr][1], acc[rr][2], acc[rr][3]);
            *(float4*)&H[(size_t)nd * 64 + tx * 4] = hv;
            if (tx == 0) { As[nd] = vs; Ad[nd] = vd; }
        }
    }
}

// ---------------------------------------------------------------------------
// Deterministic atomic-free binning into NXCD dst-range buckets.
// binA: per-(block,bucket) counts (registers -> wave reduce -> LDS -> global,
//       ZERO global atomics).
// binscan: exclusive scan of the 8*GRIDB counts, bucket-major, so each
//       (bucket, block) pair owns an exact extent of the flat bins array and
//       bucket b's range is [cnts[b*GRIDB], cnts[(b+1)*GRIDB]).
// binC: re-read chunk, place records at reserved offsets via block-local LDS
//       cursors (ballot-aggregated LDS atomics only).
// ---------------------------------------------------------------------------
__global__ __launch_bounds__(256) void binA_kernel(
    const int* __restrict__ dst, int e, int chunk,
    int* __restrict__ cnts, int lo_div)
{
    __shared__ int cnt[NXCD];
    if (threadIdx.x < NXCD) cnt[threadIdx.x] = 0;
    __syncthreads();

    const int lane = threadIdx.x & 63;
    const int beg = blockIdx.x * chunk;
    const int end = min(beg + chunk, e);

    int c[NXCD];
#pragma unroll
    for (int b = 0; b < NXCD; ++b) c[b] = 0;

    for (int i = beg + threadIdx.x; i < end; i += 256) {
        int g = __builtin_nontemporal_load(&dst[i]) / lo_div;
#pragma unroll
        for (int b = 0; b < NXCD; ++b) c[b] += (g == b);
    }
#pragma unroll
    for (int b = 0; b < NXCD; ++b) {
#pragma unroll
        for (int off = 32; off; off >>= 1) c[b] += __shfl_xor(c[b], off);
        if (lane == 0 && c[b]) atomicAdd(&cnt[b], c[b]);
    }
    __syncthreads();
    if (threadIdx.x < NXCD)
        cnts[threadIdx.x * GRIDB + blockIdx.x] = cnt[threadIdx.x];
}

__global__ __launch_bounds__(256) void binscan_kernel(int* __restrict__ cnts)
{
    // in-place exclusive scan of M = NXCD*GRIDB = 8192 ints, one block
    __shared__ int sh[256];
    const int t = threadIdx.x;
    constexpr int PER = NXCD * GRIDB / 256;  // 32
    const int base = t * PER;
    int v[PER];
#pragma unroll
    for (int j = 0; j < PER; ++j) v[j] = cnts[base + j];
    int run = 0;
#pragma unroll
    for (int j = 0; j < PER; ++j) { int x = v[j]; v[j] = run; run += x; }
    sh[t] = run;
    __syncthreads();
    for (int off = 1; off < 256; off <<= 1) {
        int x = (t >= off) ? sh[t - off] : 0;
        __syncthreads();
        sh[t] += x;
        __syncthreads();
    }
    int excl = (t > 0) ? sh[t - 1] : 0;
#pragma unroll
    for (int j = 0; j < PER; ++j) cnts[base + j] = v[j] + excl;
}

__global__ __launch_bounds__(256) void binC_kernel(
    const int* __restrict__ src, const int* __restrict__ dst, int e, int chunk,
    const int* __restrict__ cnts, int2* __restrict__ bins, int lo_div)
{
    __shared__ int cur[NXCD];
    if (threadIdx.x < NXCD)
        cur[threadIdx.x] = cnts[threadIdx.x * GRIDB + blockIdx.x];
    __syncthreads();

    const int lane = threadIdx.x & 63;
    const unsigned long long ltmask =
        (lane == 0) ? 0ull : (~0ull >> (64 - lane));
    const int beg = blockIdx.x * chunk;
    const int end = min(beg + chunk, e);

    for (int i = beg + threadIdx.x; i < end; i += 256) {
        int s = __builtin_nontemporal_load(&src[i]);
        int d = __builtin_nontemporal_load(&dst[i]);
        int g = d / lo_div;
#pragma unroll
        for (int b = 0; b < NXCD; ++b) {
            unsigned long long mask = __ballot(g == b);
            if (mask) {
                int leader = __ffsll((long long)mask) - 1;
                int base = 0;
                if (lane == leader) base = atomicAdd(&cur[b], __popcll(mask));
                base = __shfl(base, leader);
                if (g == b) {
                    int2 r; r.x = s; r.y = d;
                    bins[base + __popcll(mask & ltmask)] = r;
                }
            }
        }
    }
}

// ---------------------------------------------------------------------------
// XCD-local histogram over the group's bucket (deg slice stays in its L2).
// ---------------------------------------------------------------------------
__global__ __launch_bounds__(256) void hist2_kernel(
    const int* __restrict__ cnts, const int2* __restrict__ bins, int e,
    int* __restrict__ deg)
{
    const int g = blockIdx.x & (NXCD - 1);
    const int gi = blockIdx.x >> 3;
    const int nb = gridDim.x >> 3;
    const int beg = cnts[g * GRIDB];
    const int end = (g == NXCD - 1) ? e : cnts[(g + 1) * GRIDB];
    for (int i = beg + gi * 256 + threadIdx.x; i < end; i += nb * 256)
        atomicAdd(&deg[__builtin_nontemporal_load(&bins[i].y)], 1);
}

#define SCAN_B 256
#define SCAN_E 1024  // 4 elems per thread

__global__ __launch_bounds__(SCAN_B) void scan1_kernel(
    const int* __restrict__ deg, int n, int* __restrict__ out /* = rp+1 */,
    int* __restrict__ partials)
{
    __shared__ int sh[SCAN_B];
    const int b = blockIdx.x, t = threadIdx.x;
    const int base = b * SCAN_E + t * 4;
    int v[4];
#pragma unroll
    for (int i = 0; i < 4; ++i) {
        int idx = base + i;
        v[i] = (idx < n) ? deg[idx] : 0;
    }
    v[1] += v[0]; v[2] += v[1]; v[3] += v[2];
    sh[t] = v[3];
    __syncthreads();
    for (int off = 1; off < SCAN_B; off <<= 1) {
        int x = (t >= off) ? sh[t - off] : 0;
        __syncthreads();
        sh[t] += x;
        __syncthreads();
    }
    int excl = (t > 0) ? sh[t - 1] : 0;
#pragma unroll
    for (int i = 0; i < 4; ++i) {
        int idx = base + i;
        if (idx < n) out[idx] = v[i] + excl;  // inclusive
    }
    if (t == SCAN_B - 1) partials[b] = sh[t];
}

__global__ __launch_bounds__(256) void scan2_kernel(int* __restrict__ partials, int nb)
{
    __shared__ int sh[256];
    const int t = threadIdx.x;
    int v = (t < nb) ? partials[t] : 0;
    sh[t] = v;
    __syncthreads();
    for (int off = 1; off < 256; off <<= 1) {
        int x = (t >= off) ? sh[t - off] : 0;
        __syncthreads();
        sh[t] += x;
        __syncthreads();
    }
    if (t < nb) partials[t] = (t > 0) ? sh[t - 1] : 0;  // exclusive
}

__global__ void scan3_kernel(int* __restrict__ rp, int* __restrict__ cursor,
                             int n, const int* __restrict__ partials)
{
    int i = blockIdx.x * blockDim.x + threadIdx.x;
    if (i < n) {
        int v = rp[1 + i] + partials[i >> 10];
        rp[1 + i] = v;
        if (i + 1 < n) cursor[i + 1] = v;
    }
    if (i == 0) { rp[0] = 0; cursor[0] = 0; }
}

// ---------------------------------------------------------------------------
// XCD-local scatter: group g streams its bucket (nontemporal) and writes
// {src, leakyrelu(As[src]+Ad[dst])} into its contiguous rec region, which
// stays resident in the XCD's 4MB L2 -> writes accumulate fully.
// ---------------------------------------------------------------------------
__global__ __launch_bounds__(256) void scatter2_kernel(
    const int* __restrict__ cnts, const int2* __restrict__ bins, int e,
    int* __restrict__ cursor, int2* __restrict__ rec,
    const float* __restrict__ As, const float* __restrict__ Ad)
{
    const int g = blockIdx.x & (NXCD - 1);
    const int gi = blockIdx.x >> 3;
    const int nb = gridDim.x >> 3;
    const int beg = cnts[g * GRIDB];
    const int end = (g == NXCD - 1) ? e : cnts[(g + 1) * GRIDB];

    for (int i = beg + gi * 256 + threadIdx.x; i < end; i += nb * 256) {
        int s = __builtin_nontemporal_load(&bins[i].x);
        int d = __builtin_nontemporal_load(&bins[i].y);
        float ev = As[s] + Ad[d];
        ev = (ev >= 0.0f) ? ev : NEG_SLOPE * ev;
        int pos = atomicAdd(&cursor[d], 1);
        int2 o; o.x = s; o.y = __float_as_int(ev);
        rec[pos] = o;
    }
}

// ---------------------------------------------------------------------------
// Aggregation: one wave per destination node, XCD-swizzled.
// ---------------------------------------------------------------------------
__global__ __launch_bounds__(256) void aggr_kernel(
    const int* __restrict__ rp, const int2* __restrict__ rec,
    const float* __restrict__ Hin, const float* __restrict__ bias,
    float* __restrict__ Out, int n, int lo_div, int relu_flag)
{
    const int lane = threadIdx.x & 63;
    const int wv = threadIdx.x >> 6;
    const float b = bias[lane];

    const int g = blockIdx.x & (NXCD - 1);
    const int gi = blockIdx.x >> 3;
    const int ngb = gridDim.x >> 3;
    const int lo = g * lo_div;
    const int hi = min(lo + lo_div, n);

    for (int d = lo + gi * 4 + wv; d < hi; d += ngb * 4) {
        const int beg = rp[d], end = rp[d + 1];

        float m = -1e30f, s = 0.0f;
        for (int i = beg + lane; i < end; i += 64) {
            float e = __int_as_float(rec[i].y);
            float mn = fmaxf(m, e);
            s = s * __expf(m - mn) + __expf(e - mn);
            m = mn;
        }
#pragma unroll
        for (int off = 32; off; off >>= 1) {
            float mo = __shfl_xor(m, off);
            float so = __shfl_xor(s, off);
            float mn = fmaxf(m, mo);
            s = s * __expf(m - mn) + so * __expf(mo - mn);
            m = mn;
        }
        const float inv = 1.0f / (s + 1e-16f);

        float acc0 = 0.f, acc1 = 0.f, acc2 = 0.f, acc3 = 0.f;
        int i = beg;
        for (; i + 4 <= end; i += 4) {
            int2 r0 = rec[i + 0];
            int2 r1 = rec[i + 1];
            int2 r2 = rec[i + 2];
            int2 r3 = rec[i + 3];
            float w0 = __expf(__int_as_float(r0.y) - m) * inv;
            float w1 = __expf(__int_as_float(r1.y) - m) * inv;
            float w2 = __expf(__int_as_float(r2.y) - m) * inv;
            float w3 = __expf(__int_as_float(r3.y) - m) * inv;
            acc0 = fmaf(w0, Hin[(size_t)r0.x * 64 + lane], acc0);
            acc1 = fmaf(w1, Hin[(size_t)r1.x * 64 + lane], acc1);
            acc2 = fmaf(w2, Hin[(size_t)r2.x * 64 + lane], acc2);
            acc3 = fmaf(w3, Hin[(size_t)r3.x * 64 + lane], acc3);
        }
        for (; i < end; ++i) {
            int2 r = rec[i];
            float w = __expf(__int_as_float(r.y) - m) * inv;
            acc0 = fmaf(w, Hin[(size_t)r.x * 64 + lane], acc0);
        }

        float r = (acc0 + acc1) + (acc2 + acc3) + b;
        if (relu_flag) r = fmaxf(r, 0.0f);
        Out[(size_t)d * 64 + lane] = r;
    }
}

// ---------------------------------------------------------------------------
// Final linear [64 -> 32] + log_softmax.
// ---------------------------------------------------------------------------
__global__ __launch_bounds__(256) void lin_lsm_kernel(
    const float* __restrict__ Z, const float* __restrict__ Wl,
    const float* __restrict__ bl, float* __restrict__ out, int n)
{
    __shared__ float Ws[64 * 32];
    __shared__ float bs[32];
    for (int i = threadIdx.x; i < 64 * 32; i += 256) Ws[i] = Wl[i];
    if (threadIdx.x < 32) bs[threadIdx.x] = bl[threadIdx.x];
    __syncthreads();

    const int lane = threadIdx.x & 63;
    const int wv = threadIdx.x >> 6;
    const int half = lane >> 5;
    const int o = lane & 31;

    for (int base = (blockIdx.x * 4 + wv) * 2; base < n; base += gridDim.x * 8) {
        const int nd = base + half;
        float acc = 0.0f;
        if (nd < n) {
            const float* z = Z + (size_t)nd * 64;
#pragma unroll
            for (int k = 0; k < 64; ++k)
                acc = fmaf(z[k], Ws[k * 32 + o], acc);
            acc += bs[o];
        }
        float m = acc;
#pragma unroll
        for (int off = 16; off; off >>= 1) m = fmaxf(m, __shfl_xor(m, off, 32));
        float ex = __expf(acc - m);
        float s = ex;
#pragma unroll
        for (int off = 16; off; off >>= 1) s += __shfl_xor(s, off, 32);
        if (nd < n) out[(size_t)nd * 32 + o] = acc - m - logf(s);
    }
}

// ---------------------------------------------------------------------------
extern "C" void kernel_launch(void* const* d_in, const int* in_sizes, int n_in,
                              void* d_out, int out_size, void* d_ws, size_t ws_size,
                              hipStream_t stream)
{
    const float* x        = (const float*)d_in[0];
    const int*   ei1      = (const int*)d_in[1];
    const int*   ei2      = (const int*)d_in[2];
    const float* W1       = (const float*)d_in[3];
    const float* att_src1 = (const float*)d_in[4];
    const float* att_dst1 = (const float*)d_in[5];
    const float* b1       = (const float*)d_in[6];
    const float* W2       = (const float*)d_in[7];
    const float* att_src2 = (const float*)d_in[8];
    const float* att_dst2 = (const float*)d_in[9];
    const float* b2       = (const float*)d_in[10];
    const float* Wlin     = (const float*)d_in[11];
    const float* blin     = (const float*)d_in[12];
    float* out = (float*)d_out;

    const int n = in_sizes[0] / 128;   // 100000
    const int e = in_sizes[1] / 2;     // 1600000

    size_t off = 0;
    auto alloc = [&](size_t bytes) {
        void* p = (char*)d_ws + off;
        off += (bytes + 255) & ~(size_t)255;
        return p;
    };
    float* bufH  = (float*)alloc((size_t)n * 64 * 4);
    float* bufZ  = (float*)alloc((size_t)n * 64 * 4);
    float* As    = (float*)alloc((size_t)n * 4);
    float* Ad    = (float*)alloc((size_t)n * 4);
    int* deg     = (int*)alloc((size_t)n * 4);
    int* rp      = (int*)alloc((size_t)(n + 1) * 4);
    int* cursor  = (int*)alloc((size_t)n * 4);
    int* partials= (int*)alloc(256 * 4);
    int* cnts    = (int*)alloc((size_t)NXCD * GRIDB * 4);
    int2* rec    = (int2*)alloc((size_t)e * 8);
    // flat bins array aliases bufZ (dead during binning in both layers)
    int2* bins   = (int2*)bufZ;        // e*8B = 12.8MB <= 25.6MB

    const int nb_scan = (n + SCAN_E - 1) / SCAN_E;
    const int gN = (n + 255) / 256;
    const int gTile = (n + 63) / 64;
    const int lo_div = (n + NXCD - 1) / NXCD;
    const int gAggr = NXCD * ((lo_div + 3) / 4);
    const int gLoc = 2048;  // XCD-swizzled kernels (multiple of 8)
    const int chunk = (e + GRIDB - 1) / GRIDB;

    // ---------------- Layer 1 ----------------
    hipMemsetAsync(deg, 0, (size_t)n * 4, stream);
    binA_kernel<<<GRIDB, 256, 0, stream>>>(ei1 + e, e, chunk, cnts, lo_div);
    binscan_kernel<<<1, 256, 0, stream>>>(cnts);
    binC_kernel<<<GRIDB, 256, 0, stream>>>(ei1, ei1 + e, e, chunk, cnts, bins, lo_div);
    gemm_tile<128><<<gTile, 256, 0, stream>>>(x, W1, att_src1, att_dst1, bufH, As, Ad, n);
    hist2_kernel<<<gLoc, 256, 0, stream>>>(cnts, bins, e, deg);
    scan1_kernel<<<nb_scan, SCAN_B, 0, stream>>>(deg, n, rp + 1, partials);
    scan2_kernel<<<1, 256, 0, stream>>>(partials, nb_scan);
    scan3_kernel<<<gN, 256, 0, stream>>>(rp, cursor, n, partials);
    scatter2_kernel<<<gLoc, 256, 0, stream>>>(cnts, bins, e, cursor, rec, As, Ad);
    aggr_kernel<<<gAggr, 256, 0, stream>>>(rp, rec, bufH, b1, bufZ, n, lo_div, 1);

    // ---------------- Layer 2 ----------------
    // gemm2 must read bufZ before binC overwrites it (bins alias)
    gemm_tile<64><<<gTile, 256, 0, stream>>>(bufZ, W2, att_src2, att_dst2, bufH, As, Ad, n);
    hipMemsetAsync(deg, 0, (size_t)n * 4, stream);
    binA_kernel<<<GRIDB, 256, 0, stream>>>(ei2 + e, e, chunk, cnts, lo_div);
    binscan_kernel<<<1, 256, 0, stream>>>(cnts);
    binC_kernel<<<GRIDB, 256, 0, stream>>>(ei2, ei2 + e, e, chunk, cnts, bins, lo_div);
    hist2_kernel<<<gLoc, 256, 0, stream>>>(cnts, bins, e, deg);
    scan1_kernel<<<nb_scan, SCAN_B, 0, stream>>>(deg, n, rp + 1, partials);
    scan2_kernel<<<1, 256, 0, stream>>>(partials, nb_scan);
    scan3_kernel<<<gN, 256, 0, stream>>>(rp, cursor, n, partials);
    scatter2_kernel<<<gLoc, 256, 0, stream>>>(cnts, bins, e, cursor, rec, As, Ad);
    aggr_kernel<<<gAggr, 256, 0, stream>>>(rp, rec, bufH, b2, bufZ, n, lo_div, 0);

    // ---------------- Final linear + log_softmax ----------------
    const int gLSM = (n + 7) / 8;
    lin_lsm_kernel<<<gLSM, 256, 0, stream>>>(bufZ, Wlin, blin, out, n);
}